// Round 21
// baseline (1113.325 us; speedup 1.0000x reference)
//
#include <hip/hip_runtime.h>
#include <hip/hip_bf16.h>
#include <math.h>

// B=64, S=128, V=50257, E=1024, H=1024, G=3H=3072
#define GRU_B 64
#define GRU_S 128
#define GRU_E 1024
#define GRU_H 1024
#define GRU_G 3072

#define XP_TILES 1536     // 64 s-pairs x 24 n-tiles
#define NPROD    192      // producer blocks

typedef _Float16 half8 __attribute__((ext_vector_type(8)));
typedef _Float16 half4v __attribute__((ext_vector_type(4)));
typedef float floatx4 __attribute__((ext_vector_type(4)));

__device__ __forceinline__ half8 cvt_h8(float4 a, float4 b) {
    half8 r;
    r[0] = (_Float16)a.x; r[1] = (_Float16)a.y;
    r[2] = (_Float16)a.z; r[3] = (_Float16)a.w;
    r[4] = (_Float16)b.x; r[5] = (_Float16)b.y;
    r[6] = (_Float16)b.z; r[7] = (_Float16)b.w;
    return r;
}

// ---------------------------------------------------------------------------
// Fused persistent kernel. R17/R19 structure + R20 incremental consumption,
// extended to a 4-WAY SPLIT:
//   quarter q: chunks [8q, 8q+8) consume h columns written by blocks
//   [16q, 16q+16) -> gated on flags[16q..16q+16). Subsequent waits re-check
//   the cached fl vector first (zero extra RTT when already satisfied).
// Publish side (block syncthreads + t0 single flag store) unchanged.
// ---------------------------------------------------------------------------
__global__ __launch_bounds__(256) void gru_fused(
    const int* __restrict__ tokens,     // [B][S]
    const float* __restrict__ emb,      // [V][E]
    const float* __restrict__ w_ih,     // [G][E]
    const float* __restrict__ b_ih,     // [G]
    _Float16* __restrict__ xproj,       // [S][B][G] fp16 (produced here)
    const float* __restrict__ w_hh,     // [G][H]
    const float* __restrict__ b_hh,     // [G]
    _Float16* __restrict__ ring,        // 128 x [64][1024] fp16
    float* __restrict__ out,            // [64][1024]
    int* __restrict__ flags,            // [64] gru step flags (zeroed)
    int* __restrict__ xpcnt)            // [64] per-s-pair tile counters (zeroed)
{
    __shared__ __attribute__((aligned(16))) char sh[96 * 1024];

    // one-time: drop stale (poison / previous-replay) lines from this XCD
    __builtin_amdgcn_fence(__ATOMIC_ACQUIRE, "agent");

    const int bid = blockIdx.x;
    const int t   = threadIdx.x;
    const int l   = t & 63;
    const int wid = t >> 6;

    const int xcd = bid & 7;

    if (xcd >= 2) {
        // ================= producer path (XCDs 2..7) — unchanged ==========
        const int pid = (bid >> 3) * 6 + (xcd - 2);   // 0..191

        _Float16* Al = reinterpret_cast<_Float16*>(sh);          // 128*32
        _Float16* Bl = Al + 128 * 32;
        int* toks    = reinterpret_cast<int*>(Bl + 128 * 32);

        const int wm   = (wid >> 1) * 64;
        const int wn   = (wid & 1) * 64;
        const int sr   = t >> 1;
        const int skw  = (sr >> 1) & 3;
        const int gb   = (t & 1) * 2;
        const int fr   = l & 15;
        const int ag   = l >> 4;
        const int skey = (fr >> 1) & 3;
        const int gfr  = (ag ^ skey) * 16;
        const int cr   = (l >> 4) * 4;
        const int cc   = l & 15;
        const bool leader = ((l & 3) == 0);

        char* ab = reinterpret_cast<char*>(Al);
        char* bb = reinterpret_cast<char*>(Bl);
        unsigned long long* xp64 = reinterpret_cast<unsigned long long*>(xproj);

        for (int T = pid; T < XP_TILES; T += NPROD) {
            const int sp = T / 24;          // s-pair (s = 2sp, 2sp+1)
            const int nt = T % 24;
            const int m0 = sp * 128;
            const int n0 = nt * 128;

            if (t < 128) {
                int m = m0 + t;
                toks[t] = tokens[(m & 63) * GRU_S + (m >> 6)];   // tokens[b][s]
            }

            floatx4 acc[4][4];
#pragma unroll
            for (int i = 0; i < 4; ++i)
#pragma unroll
                for (int jj = 0; jj < 4; ++jj)
                    acc[i][jj] = (floatx4){0.f, 0.f, 0.f, 0.f};

            for (int k0 = 0; k0 < GRU_E; k0 += 32) {
                __syncthreads();   // covers toks + prev tile LDS reuse
                {
                    const float4* asrc = reinterpret_cast<const float4*>(
                        emb + (size_t)toks[sr] * GRU_E + k0 + (t & 1) * 16);
                    const float4* bsrc = reinterpret_cast<const float4*>(
                        w_ih + (size_t)(n0 + sr) * GRU_E + k0 + (t & 1) * 16);
                    float4 a0 = asrc[0], a1 = asrc[1], a2 = asrc[2], a3 = asrc[3];
                    float4 b0 = bsrc[0], b1 = bsrc[1], b2 = bsrc[2], b3 = bsrc[3];
                    *reinterpret_cast<half8*>(ab + sr * 64 + ((gb + 0) ^ skw) * 16) = cvt_h8(a0, a1);
                    *reinterpret_cast<half8*>(ab + sr * 64 + ((gb + 1) ^ skw) * 16) = cvt_h8(a2, a3);
                    *reinterpret_cast<half8*>(bb + sr * 64 + ((gb + 0) ^ skw) * 16) = cvt_h8(b0, b1);
                    *reinterpret_cast<half8*>(bb + sr * 64 + ((gb + 1) ^ skw) * 16) = cvt_h8(b2, b3);
                }
                __syncthreads();

                half8 a4[4], b4[4];
#pragma unroll
                for (int mi = 0; mi < 4; ++mi)
                    a4[mi] = *reinterpret_cast<const half8*>(ab + (wm + mi * 16 + fr) * 64 + gfr);
#pragma unroll
                for (int ni = 0; ni < 4; ++ni)
                    b4[ni] = *reinterpret_cast<const half8*>(bb + (wn + ni * 16 + fr) * 64 + gfr);
#pragma unroll
                for (int mi = 0; mi < 4; ++mi)
#pragma unroll
                    for (int ni = 0; ni < 4; ++ni)
                        acc[mi][ni] = __builtin_amdgcn_mfma_f32_16x16x32_f16(
                            a4[mi], b4[ni], acc[mi][ni], 0, 0, 0);
            }

            // epilogue: pack 4 adjacent-n halves -> agent swap to MALL (R14)
#pragma unroll
            for (int ni = 0; ni < 4; ++ni) {
                const int n = n0 + wn + ni * 16 + cc;
                const float bias = b_ih[n];
                const int nb4 = (n0 + wn + ni * 16 + (cc & ~3)) >> 2;  // ull col
#pragma unroll
                for (int mi = 0; mi < 4; ++mi) {
#pragma unroll
                    for (int q = 0; q < 4; ++q) {
                        const int m = m0 + wm + mi * 16 + cr + q;
                        float v = acc[mi][ni][q] + bias;
                        unsigned int hu = (unsigned int)__builtin_bit_cast(
                            unsigned short, (_Float16)v);
                        unsigned int ot = (unsigned int)__shfl_xor((int)hu, 1);
                        unsigned int dwq = hu | (ot << 16);
                        unsigned int hi = (unsigned int)__shfl_xor((int)dwq, 2);
                        if (leader) {
                            unsigned long long qw =
                                (unsigned long long)dwq |
                                ((unsigned long long)hi << 32);
                            (void)__hip_atomic_exchange(
                                xp64 + (size_t)m * (GRU_G / 4) + nb4, qw,
                                __ATOMIC_RELAXED, __HIP_MEMORY_SCOPE_AGENT);
                        }
                    }
                }
            }

            __syncthreads();   // per-wave vmcnt(0): swaps at MALL; LDS guard
            if (t == 0)
                __hip_atomic_fetch_add(xpcnt + sp, 1, __ATOMIC_RELAXED,
                                       __HIP_MEMORY_SCOPE_AGENT);
        }
        return;
    }

    // ================= gru consumer path (XCDs 0,1) ========================
    const int jb = (bid >> 3) * 2 + xcd;    // 0..63
    _Float16* wlds = reinterpret_cast<_Float16*>(sh);            // 48*1024

    const int m0 = wid * 16;

    const size_t BUFE = (size_t)GRU_B * GRU_H;       // halves per ring buffer
    const size_t BUFQ = BUFE / 4;                    // ulls per ring buffer

    // ---- stage W: 48 rows (gate*16+jloc), fp32 -> fp16, swizzled ----
    {
        char* wbp = reinterpret_cast<char*>(wlds);
        for (int r = 0; r < 48; ++r) {
            int grow = (r >> 4) * GRU_H + jb * 16 + (r & 15);
            float4 v = reinterpret_cast<const float4*>(
                w_hh + (size_t)grow * GRU_H)[t];
            half4v hv;
            hv.x = (_Float16)v.x; hv.y = (_Float16)v.y;
            hv.z = (_Float16)v.z; hv.w = (_Float16)v.w;
            int g = (t >> 1) ^ (r & 7);
            *reinterpret_cast<half4v*>(wbp + r * 2048 + g * 16 + (t & 1) * 8) = hv;
        }
    }

    // ---- zero h(0) = ring slot 127 via IF swaps (proven init) ----
    {
        unsigned long long* z =
            reinterpret_cast<unsigned long long*>(ring) + 127 * BUFQ;
        int i0 = jb * 256 + t;          // 16384 ull
        (void)__hip_atomic_exchange(z + i0, 0ULL, __ATOMIC_RELAXED,
                                    __HIP_MEMORY_SCOPE_AGENT);
    }

    // ---- per-thread constants ----
    const int jl   = l & 15;
    const int qrow = (l >> 4) * 4;
    const int j    = jb * 16 + jl;
    const float bhr = b_hh[j];
    const float bhz = b_hh[GRU_H + j];
    const float bhn = b_hh[2 * GRU_H + j];

    const int arow  = m0 + (l & 15);         // A-frag h row
    const int akoff = (l >> 4) * 8;          // A-frag k offset (halves)
    const int sk    = jl & 7;
    const char* wb  = reinterpret_cast<const char*>(wlds);
    const int bbase0 = (0 * 16 + jl) * 2048;
    const int bbase1 = (1 * 16 + jl) * 2048;
    const int bbase2 = (2 * 16 + jl) * 2048;

    const int colq   = (jb * 16 + jl) >> 2;  // ull column (256 per row)
    const bool leader = ((l & 3) == 0);

    float hp[4] = {0.f, 0.f, 0.f, 0.f};
    float xr[4], xz[4], xnn[4];

    // ---- initial publish: W staged + zero-swaps acked -> flag = 1 ----
    __syncthreads();                         // per-wave vmcnt(0) drains swaps
    if (t == 0)
        __hip_atomic_store(flags + jb, 1, __ATOMIC_RELAXED,
                           __HIP_MEMORY_SCOPE_AGENT);

    // ---- wait for xproj slab pair 0, then prefetch step 0 ----
    while (__hip_atomic_load(xpcnt + 0, __ATOMIC_RELAXED,
                             __HIP_MEMORY_SCOPE_AGENT) < 24)
        __builtin_amdgcn_s_sleep(2);
    asm volatile("" ::: "memory");
#pragma unroll
    for (int q = 0; q < 4; ++q) {
        const _Float16* row = xproj + (size_t)(m0 + qrow + q) * GRU_G;
        xr[q]  = (float)row[j];
        xz[q]  = (float)row[GRU_H + j];
        xnn[q] = (float)row[2 * GRU_H + j];
    }

    int last_ver = 0;   // highest xproj slab already verified complete

    for (int s = 0; s < GRU_S; ++s) {
        const int tgt = s + 1;
        const int lq  = l >> 4;          // lane's quarter (0..3)

        const _Float16* hbuf = ring + (size_t)(127 - s) * BUFE;
        const _Float16* aptr = hbuf + (size_t)arow * GRU_H + akoff;

        floatx4 acc0 = {0.f, 0.f, 0.f, 0.f};
        floatx4 acc1 = {0.f, 0.f, 0.f, 0.f};
        floatx4 acc2 = {0.f, 0.f, 0.f, 0.f};

        // ---- 4-way incremental wait+consume ----
        int fl = __hip_atomic_load(flags + l, __ATOMIC_RELAXED,
                                   __HIP_MEMORY_SCOPE_AGENT);
#pragma unroll
        for (int q4 = 0; q4 < 4; ++q4) {
            // quarter q4: chunks [8q4, 8q4+8) gated by flags[16q4..16q4+16)
            if (q4 == 0) {
                while (!__all((lq != q4) | (fl >= tgt))) {
                    __builtin_amdgcn_s_sleep(1);
                    fl = __hip_atomic_load(flags + l, __ATOMIC_RELAXED,
                                           __HIP_MEMORY_SCOPE_AGENT);
                }
            } else {
                while (!__all((lq != q4) | (fl >= tgt))) {
                    fl = __hip_atomic_load(flags + l, __ATOMIC_RELAXED,
                                           __HIP_MEMORY_SCOPE_AGENT);
                }
            }
            __builtin_amdgcn_sched_barrier(0);
            asm volatile("" ::: "memory");   // pin this quarter's h loads

#pragma unroll
            for (int kk = 0; kk < 8; ++kk) {
                const int kc = q4 * 8 + kk;
                half8 a = *reinterpret_cast<const half8*>(aptr + kc * 32);
                int g = (kc * 4 + (l >> 4)) ^ sk;
                half8 b0 = *reinterpret_cast<const half8*>(wb + bbase0 + g * 16);
                half8 b1 = *reinterpret_cast<const half8*>(wb + bbase1 + g * 16);
                half8 b2 = *reinterpret_cast<const half8*>(wb + bbase2 + g * 16);
                acc0 = __builtin_amdgcn_mfma_f32_16x16x32_f16(a, b0, acc0, 0, 0, 0);
                acc1 = __builtin_amdgcn_mfma_f32_16x16x32_f16(a, b1, acc1, 0, 0, 0);
                acc2 = __builtin_amdgcn_mfma_f32_16x16x32_f16(a, b2, acc2, 0, 0, 0);
            }
        }

        const bool last = (s == GRU_S - 1);

        // ---- fused gate epilogue ----
        unsigned int dw[4];
#pragma unroll
        for (int q = 0; q < 4; ++q) {
            float r  = 1.f / (1.f + __expf(-(xr[q] + acc0[q] + bhr)));
            float zg = 1.f / (1.f + __expf(-(xz[q] + acc1[q] + bhz)));
            float pre = xnn[q] + r * (acc2[q] + bhn);
            pre = fminf(fmaxf(pre, -15.f), 15.f);
            float e2 = __expf(2.f * pre);
            float ng = (e2 - 1.f) / (e2 + 1.f);
            float h  = (1.f - zg) * ng + zg * hp[q];
            hp[q] = h;
            unsigned int hu = (unsigned int)__builtin_bit_cast(
                unsigned short, (_Float16)h);
            unsigned int ot = (unsigned int)__shfl_xor((int)hu, 1);
            dw[q] = hu | (ot << 16);
        }

        if (!last) {
            // publish h(s+1) into fresh slot 126-s (quad-pack swaps, proven)
            unsigned long long* wbuf =
                reinterpret_cast<unsigned long long*>(ring)
                + (size_t)(126 - s) * BUFQ;
#pragma unroll
            for (int q = 0; q < 4; ++q) {
                unsigned int hi = (unsigned int)__shfl_xor((int)dw[q], 2);
                if (leader) {
                    unsigned long long qw =
                        (unsigned long long)dw[q] |
                        ((unsigned long long)hi << 32);
                    (void)__hip_atomic_exchange(
                        wbuf + (size_t)(m0 + qrow + q) * 256 + colq, qw,
                        __ATOMIC_RELAXED, __HIP_MEMORY_SCOPE_AGENT);
                }
            }

            __syncthreads();             // per-wave vmcnt(0): swaps at IF
            if (t == 0)
                __hip_atomic_store(flags + jb, s + 2, __ATOMIC_RELAXED,
                                   __HIP_MEMORY_SCOPE_AGENT);
            asm volatile("" ::: "memory");

            // gate on xproj slab (s+1) ONLY when the slab index advances
            const int spn = (s + 1) >> 1;
            if (spn != last_ver) {
                while (__hip_atomic_load(xpcnt + spn, __ATOMIC_RELAXED,
                                         __HIP_MEMORY_SCOPE_AGENT) < 24)
                    __builtin_amdgcn_s_sleep(2);
                last_ver = spn;
            }
            asm volatile("" ::: "memory");
            const _Float16* xpS = xproj + (size_t)(s + 1) * (GRU_B * GRU_G);
#pragma unroll
            for (int q = 0; q < 4; ++q) {
                const _Float16* row = xpS + (size_t)(m0 + qrow + q) * GRU_G;
                xr[q]  = (float)row[j];
                xz[q]  = (float)row[GRU_H + j];
                xnn[q] = (float)row[2 * GRU_H + j];
            }
        }
    }

    // final hidden state -> output (fp32, plain stores)
#pragma unroll
    for (int q = 0; q < 4; ++q)
        out[(size_t)(m0 + qrow + q) * GRU_H + j] = hp[q];
}

// ---------------------------------------------------------------------------
// Launch
// ---------------------------------------------------------------------------
extern "C" void kernel_launch(void* const* d_in, const int* in_sizes, int n_in,
                              void* d_out, int out_size, void* d_ws, size_t ws_size,
                              hipStream_t stream) {
    const int*   tokens = (const int*)  d_in[0];
    const float* emb    = (const float*)d_in[1];
    const float* w_ih   = (const float*)d_in[2];
    const float* w_hh   = (const float*)d_in[3];
    const float* b_ih   = (const float*)d_in[4];
    const float* b_hh   = (const float*)d_in[5];
    float* out = (float*)d_out;

    // ws layout: xproj fp16 (50.3 MB) | ring 128x128KB (16.8 MB) | flags+xpcnt
    _Float16* xproj16 = (_Float16*)d_ws;
    _Float16* ring    = xproj16 + (size_t)GRU_S * GRU_B * GRU_G;
    int*      flags   = (int*)(ring + 128 * (size_t)GRU_B * GRU_H);   // [64]
    int*      xpcnt   = flags + 64;                                   // [64]

    hipMemsetAsync(flags, 0, 128 * sizeof(int), stream);

    {
        const int* tok_a = tokens;
        const float* emb_a = emb;
        const float* wih_a = w_ih;
        const float* bih_a = b_ih;
        _Float16* xp_a = xproj16;
        const float* whh_a = w_hh;
        const float* bhh_a = b_hh;
        _Float16* ring_a = ring;
        float* out_a = out;
        int* flags_a = flags;
        int* xpcnt_a = xpcnt;
        void* args[] = { (void*)&tok_a, (void*)&emb_a, (void*)&wih_a,
                         (void*)&bih_a, (void*)&xp_a, (void*)&whh_a,
                         (void*)&bhh_a, (void*)&ring_a, (void*)&out_a,
                         (void*)&flags_a, (void*)&xpcnt_a };
        hipLaunchCooperativeKernel((void*)gru_fused, dim3(256), dim3(256),
                                   args, 0, stream);
    }
}

// Round 22
// 802.943 us; speedup vs baseline: 1.3866x; 1.3866x over previous
//
#include <hip/hip_runtime.h>
#include <hip/hip_bf16.h>
#include <math.h>

// B=64, S=128, V=50257, E=1024, H=1024, G=3H=3072
#define GRU_B 64
#define GRU_S 128
#define GRU_E 1024
#define GRU_H 1024
#define GRU_G 3072

#define XP_TILES 1536     // 64 s-pairs x 24 n-tiles
#define NPROD    192      // producer blocks

typedef _Float16 half8 __attribute__((ext_vector_type(8)));
typedef _Float16 half4v __attribute__((ext_vector_type(4)));
typedef float floatx4 __attribute__((ext_vector_type(4)));

__device__ __forceinline__ half8 cvt_h8(float4 a, float4 b) {
    half8 r;
    r[0] = (_Float16)a.x; r[1] = (_Float16)a.y;
    r[2] = (_Float16)a.z; r[3] = (_Float16)a.w;
    r[4] = (_Float16)b.x; r[5] = (_Float16)b.y;
    r[6] = (_Float16)b.z; r[7] = (_Float16)b.w;
    return r;
}

// ---------------------------------------------------------------------------
// Fused persistent kernel. R20 configuration (proven best: 804 us total):
//   XCDs 0,1 -> 64 gru consumers; XCDs 2-7 -> 192 xproj producers (R14 swap
//   epilogue). gru: R12 fresh-region ring + SPLIT-HALF incremental
//   consumption (wait flags[0..31] -> chunks 0..15; wait flags[32..63] ->
//   chunks 16..31). R21's 4-way split REVERTED (load fragmentation, -38%).
// ---------------------------------------------------------------------------
__global__ __launch_bounds__(256) void gru_fused(
    const int* __restrict__ tokens,     // [B][S]
    const float* __restrict__ emb,      // [V][E]
    const float* __restrict__ w_ih,     // [G][E]
    const float* __restrict__ b_ih,     // [G]
    _Float16* __restrict__ xproj,       // [S][B][G] fp16 (produced here)
    const float* __restrict__ w_hh,     // [G][H]
    const float* __restrict__ b_hh,     // [G]
    _Float16* __restrict__ ring,        // 128 x [64][1024] fp16
    float* __restrict__ out,            // [64][1024]
    int* __restrict__ flags,            // [64] gru step flags (zeroed)
    int* __restrict__ xpcnt)            // [64] per-s-pair tile counters (zeroed)
{
    __shared__ __attribute__((aligned(16))) char sh[96 * 1024];

    // one-time: drop stale (poison / previous-replay) lines from this XCD
    __builtin_amdgcn_fence(__ATOMIC_ACQUIRE, "agent");

    const int bid = blockIdx.x;
    const int t   = threadIdx.x;
    const int l   = t & 63;
    const int wid = t >> 6;

    const int xcd = bid & 7;

    if (xcd >= 2) {
        // ================= producer path (XCDs 2..7) =================
        const int pid = (bid >> 3) * 6 + (xcd - 2);   // 0..191

        _Float16* Al = reinterpret_cast<_Float16*>(sh);          // 128*32
        _Float16* Bl = Al + 128 * 32;
        int* toks    = reinterpret_cast<int*>(Bl + 128 * 32);

        const int wm   = (wid >> 1) * 64;
        const int wn   = (wid & 1) * 64;
        const int sr   = t >> 1;
        const int skw  = (sr >> 1) & 3;
        const int gb   = (t & 1) * 2;
        const int fr   = l & 15;
        const int ag   = l >> 4;
        const int skey = (fr >> 1) & 3;
        const int gfr  = (ag ^ skey) * 16;
        const int cr   = (l >> 4) * 4;
        const int cc   = l & 15;
        const bool leader = ((l & 3) == 0);

        char* ab = reinterpret_cast<char*>(Al);
        char* bb = reinterpret_cast<char*>(Bl);
        unsigned long long* xp64 = reinterpret_cast<unsigned long long*>(xproj);

        for (int T = pid; T < XP_TILES; T += NPROD) {
            const int sp = T / 24;          // s-pair (s = 2sp, 2sp+1)
            const int nt = T % 24;
            const int m0 = sp * 128;
            const int n0 = nt * 128;

            if (t < 128) {
                int m = m0 + t;
                toks[t] = tokens[(m & 63) * GRU_S + (m >> 6)];   // tokens[b][s]
            }

            floatx4 acc[4][4];
#pragma unroll
            for (int i = 0; i < 4; ++i)
#pragma unroll
                for (int jj = 0; jj < 4; ++jj)
                    acc[i][jj] = (floatx4){0.f, 0.f, 0.f, 0.f};

            for (int k0 = 0; k0 < GRU_E; k0 += 32) {
                __syncthreads();   // covers toks + prev tile LDS reuse
                {
                    const float4* asrc = reinterpret_cast<const float4*>(
                        emb + (size_t)toks[sr] * GRU_E + k0 + (t & 1) * 16);
                    const float4* bsrc = reinterpret_cast<const float4*>(
                        w_ih + (size_t)(n0 + sr) * GRU_E + k0 + (t & 1) * 16);
                    float4 a0 = asrc[0], a1 = asrc[1], a2 = asrc[2], a3 = asrc[3];
                    float4 b0 = bsrc[0], b1 = bsrc[1], b2 = bsrc[2], b3 = bsrc[3];
                    *reinterpret_cast<half8*>(ab + sr * 64 + ((gb + 0) ^ skw) * 16) = cvt_h8(a0, a1);
                    *reinterpret_cast<half8*>(ab + sr * 64 + ((gb + 1) ^ skw) * 16) = cvt_h8(a2, a3);
                    *reinterpret_cast<half8*>(bb + sr * 64 + ((gb + 0) ^ skw) * 16) = cvt_h8(b0, b1);
                    *reinterpret_cast<half8*>(bb + sr * 64 + ((gb + 1) ^ skw) * 16) = cvt_h8(b2, b3);
                }
                __syncthreads();

                half8 a4[4], b4[4];
#pragma unroll
                for (int mi = 0; mi < 4; ++mi)
                    a4[mi] = *reinterpret_cast<const half8*>(ab + (wm + mi * 16 + fr) * 64 + gfr);
#pragma unroll
                for (int ni = 0; ni < 4; ++ni)
                    b4[ni] = *reinterpret_cast<const half8*>(bb + (wn + ni * 16 + fr) * 64 + gfr);
#pragma unroll
                for (int mi = 0; mi < 4; ++mi)
#pragma unroll
                    for (int ni = 0; ni < 4; ++ni)
                        acc[mi][ni] = __builtin_amdgcn_mfma_f32_16x16x32_f16(
                            a4[mi], b4[ni], acc[mi][ni], 0, 0, 0);
            }

            // epilogue: pack 4 adjacent-n halves -> agent swap to MALL (R14)
#pragma unroll
            for (int ni = 0; ni < 4; ++ni) {
                const int n = n0 + wn + ni * 16 + cc;
                const float bias = b_ih[n];
                const int nb4 = (n0 + wn + ni * 16 + (cc & ~3)) >> 2;  // ull col
#pragma unroll
                for (int mi = 0; mi < 4; ++mi) {
#pragma unroll
                    for (int q = 0; q < 4; ++q) {
                        const int m = m0 + wm + mi * 16 + cr + q;
                        float v = acc[mi][ni][q] + bias;
                        unsigned int hu = (unsigned int)__builtin_bit_cast(
                            unsigned short, (_Float16)v);
                        unsigned int ot = (unsigned int)__shfl_xor((int)hu, 1);
                        unsigned int dwq = hu | (ot << 16);
                        unsigned int hi = (unsigned int)__shfl_xor((int)dwq, 2);
                        if (leader) {
                            unsigned long long qw =
                                (unsigned long long)dwq |
                                ((unsigned long long)hi << 32);
                            (void)__hip_atomic_exchange(
                                xp64 + (size_t)m * (GRU_G / 4) + nb4, qw,
                                __ATOMIC_RELAXED, __HIP_MEMORY_SCOPE_AGENT);
                        }
                    }
                }
            }

            __syncthreads();   // per-wave vmcnt(0): swaps at MALL; LDS guard
            if (t == 0)
                __hip_atomic_fetch_add(xpcnt + sp, 1, __ATOMIC_RELAXED,
                                       __HIP_MEMORY_SCOPE_AGENT);
        }
        return;
    }

    // ================= gru consumer path (XCDs 0,1) ========================
    const int jb = (bid >> 3) * 2 + xcd;    // 0..63
    _Float16* wlds = reinterpret_cast<_Float16*>(sh);            // 48*1024

    const int m0 = wid * 16;

    const size_t BUFE = (size_t)GRU_B * GRU_H;       // halves per ring buffer
    const size_t BUFQ = BUFE / 4;                    // ulls per ring buffer

    // ---- stage W: 48 rows (gate*16+jloc), fp32 -> fp16, swizzled ----
    {
        char* wbp = reinterpret_cast<char*>(wlds);
        for (int r = 0; r < 48; ++r) {
            int grow = (r >> 4) * GRU_H + jb * 16 + (r & 15);
            float4 v = reinterpret_cast<const float4*>(
                w_hh + (size_t)grow * GRU_H)[t];
            half4v hv;
            hv.x = (_Float16)v.x; hv.y = (_Float16)v.y;
            hv.z = (_Float16)v.z; hv.w = (_Float16)v.w;
            int g = (t >> 1) ^ (r & 7);
            *reinterpret_cast<half4v*>(wbp + r * 2048 + g * 16 + (t & 1) * 8) = hv;
        }
    }

    // ---- zero h(0) = ring slot 127 via IF swaps (proven init) ----
    {
        unsigned long long* z =
            reinterpret_cast<unsigned long long*>(ring) + 127 * BUFQ;
        int i0 = jb * 256 + t;          // 16384 ull
        (void)__hip_atomic_exchange(z + i0, 0ULL, __ATOMIC_RELAXED,
                                    __HIP_MEMORY_SCOPE_AGENT);
    }

    // ---- per-thread constants ----
    const int jl   = l & 15;
    const int qrow = (l >> 4) * 4;
    const int j    = jb * 16 + jl;
    const float bhr = b_hh[j];
    const float bhz = b_hh[GRU_H + j];
    const float bhn = b_hh[2 * GRU_H + j];

    const int arow  = m0 + (l & 15);         // A-frag h row
    const int akoff = (l >> 4) * 8;          // A-frag k offset (halves)
    const int sk    = jl & 7;
    const char* wb  = reinterpret_cast<const char*>(wlds);
    const int bbase0 = (0 * 16 + jl) * 2048;
    const int bbase1 = (1 * 16 + jl) * 2048;
    const int bbase2 = (2 * 16 + jl) * 2048;

    const int colq   = (jb * 16 + jl) >> 2;  // ull column (256 per row)
    const bool leader = ((l & 3) == 0);

    float hp[4] = {0.f, 0.f, 0.f, 0.f};
    float xr[4], xz[4], xnn[4];

    // ---- initial publish: W staged + zero-swaps acked -> flag = 1 ----
    __syncthreads();                         // per-wave vmcnt(0) drains swaps
    if (t == 0)
        __hip_atomic_store(flags + jb, 1, __ATOMIC_RELAXED,
                           __HIP_MEMORY_SCOPE_AGENT);

    // ---- wait for xproj slab pair 0, then prefetch step 0 ----
    while (__hip_atomic_load(xpcnt + 0, __ATOMIC_RELAXED,
                             __HIP_MEMORY_SCOPE_AGENT) < 24)
        __builtin_amdgcn_s_sleep(2);
    asm volatile("" ::: "memory");
#pragma unroll
    for (int q = 0; q < 4; ++q) {
        const _Float16* row = xproj + (size_t)(m0 + qrow + q) * GRU_G;
        xr[q]  = (float)row[j];
        xz[q]  = (float)row[GRU_H + j];
        xnn[q] = (float)row[2 * GRU_H + j];
    }

    int last_ver = 0;   // highest xproj slab already verified complete

    for (int s = 0; s < GRU_S; ++s) {
        const int tgt = s + 1;

        // ---- split-half wait: every wave polls (lane l <-> flags[l]) ----
        int fl = __hip_atomic_load(flags + l, __ATOMIC_RELAXED,
                                   __HIP_MEMORY_SCOPE_AGENT);
        // lower half: producers 0..31 (h columns 0..511)
        while (!__all((l >= 32) | (fl >= tgt))) {
            __builtin_amdgcn_s_sleep(1);
            fl = __hip_atomic_load(flags + l, __ATOMIC_RELAXED,
                                   __HIP_MEMORY_SCOPE_AGENT);
        }
        __builtin_amdgcn_sched_barrier(0);
        asm volatile("" ::: "memory");   // pin lower-half h loads after poll

        const _Float16* hbuf = ring + (size_t)(127 - s) * BUFE;
        const _Float16* aptr = hbuf + (size_t)arow * GRU_H + akoff;

        floatx4 acc0 = {0.f, 0.f, 0.f, 0.f};
        floatx4 acc1 = {0.f, 0.f, 0.f, 0.f};
        floatx4 acc2 = {0.f, 0.f, 0.f, 0.f};

#pragma unroll 8
        for (int kc = 0; kc < 16; ++kc) {
            half8 a = *reinterpret_cast<const half8*>(aptr + kc * 32);
            int g = (kc * 4 + (l >> 4)) ^ sk;
            half8 b0 = *reinterpret_cast<const half8*>(wb + bbase0 + g * 16);
            half8 b1 = *reinterpret_cast<const half8*>(wb + bbase1 + g * 16);
            half8 b2 = *reinterpret_cast<const half8*>(wb + bbase2 + g * 16);
            acc0 = __builtin_amdgcn_mfma_f32_16x16x32_f16(a, b0, acc0, 0, 0, 0);
            acc1 = __builtin_amdgcn_mfma_f32_16x16x32_f16(a, b1, acc1, 0, 0, 0);
            acc2 = __builtin_amdgcn_mfma_f32_16x16x32_f16(a, b2, acc2, 0, 0, 0);
        }

        // upper half: producers 32..63 (h columns 512..1023)
        while (!__all((l < 32) | (fl >= tgt))) {
            fl = __hip_atomic_load(flags + l, __ATOMIC_RELAXED,
                                   __HIP_MEMORY_SCOPE_AGENT);
        }
        __builtin_amdgcn_sched_barrier(0);
        asm volatile("" ::: "memory");   // pin upper-half h loads after poll

#pragma unroll 8
        for (int kc = 16; kc < 32; ++kc) {
            half8 a = *reinterpret_cast<const half8*>(aptr + kc * 32);
            int g = (kc * 4 + (l >> 4)) ^ sk;
            half8 b0 = *reinterpret_cast<const half8*>(wb + bbase0 + g * 16);
            half8 b1 = *reinterpret_cast<const half8*>(wb + bbase1 + g * 16);
            half8 b2 = *reinterpret_cast<const half8*>(wb + bbase2 + g * 16);
            acc0 = __builtin_amdgcn_mfma_f32_16x16x32_f16(a, b0, acc0, 0, 0, 0);
            acc1 = __builtin_amdgcn_mfma_f32_16x16x32_f16(a, b1, acc1, 0, 0, 0);
            acc2 = __builtin_amdgcn_mfma_f32_16x16x32_f16(a, b2, acc2, 0, 0, 0);
        }

        const bool last = (s == GRU_S - 1);

        // ---- fused gate epilogue ----
        unsigned int dw[4];
#pragma unroll
        for (int q = 0; q < 4; ++q) {
            float r  = 1.f / (1.f + __expf(-(xr[q] + acc0[q] + bhr)));
            float zg = 1.f / (1.f + __expf(-(xz[q] + acc1[q] + bhz)));
            float pre = xnn[q] + r * (acc2[q] + bhn);
            pre = fminf(fmaxf(pre, -15.f), 15.f);
            float e2 = __expf(2.f * pre);
            float ng = (e2 - 1.f) / (e2 + 1.f);
            float h  = (1.f - zg) * ng + zg * hp[q];
            hp[q] = h;
            unsigned int hu = (unsigned int)__builtin_bit_cast(
                unsigned short, (_Float16)h);
            unsigned int ot = (unsigned int)__shfl_xor((int)hu, 1);
            dw[q] = hu | (ot << 16);
        }

        if (!last) {
            // publish h(s+1) into fresh slot 126-s (quad-pack swaps, proven)
            unsigned long long* wbuf =
                reinterpret_cast<unsigned long long*>(ring)
                + (size_t)(126 - s) * BUFQ;
#pragma unroll
            for (int q = 0; q < 4; ++q) {
                unsigned int hi = (unsigned int)__shfl_xor((int)dw[q], 2);
                if (leader) {
                    unsigned long long qw =
                        (unsigned long long)dw[q] |
                        ((unsigned long long)hi << 32);
                    (void)__hip_atomic_exchange(
                        wbuf + (size_t)(m0 + qrow + q) * 256 + colq, qw,
                        __ATOMIC_RELAXED, __HIP_MEMORY_SCOPE_AGENT);
                }
            }

            __syncthreads();             // per-wave vmcnt(0): swaps at IF
            if (t == 0)
                __hip_atomic_store(flags + jb, s + 2, __ATOMIC_RELAXED,
                                   __HIP_MEMORY_SCOPE_AGENT);
            asm volatile("" ::: "memory");

            // gate on xproj slab (s+1) ONLY when the slab index advances
            const int spn = (s + 1) >> 1;
            if (spn != last_ver) {
                while (__hip_atomic_load(xpcnt + spn, __ATOMIC_RELAXED,
                                         __HIP_MEMORY_SCOPE_AGENT) < 24)
                    __builtin_amdgcn_s_sleep(2);
                last_ver = spn;
            }
            asm volatile("" ::: "memory");
            const _Float16* xpS = xproj + (size_t)(s + 1) * (GRU_B * GRU_G);
#pragma unroll
            for (int q = 0; q < 4; ++q) {
                const _Float16* row = xpS + (size_t)(m0 + qrow + q) * GRU_G;
                xr[q]  = (float)row[j];
                xz[q]  = (float)row[GRU_H + j];
                xnn[q] = (float)row[2 * GRU_H + j];
            }
        }
    }

    // final hidden state -> output (fp32, plain stores)
#pragma unroll
    for (int q = 0; q < 4; ++q)
        out[(size_t)(m0 + qrow + q) * GRU_H + j] = hp[q];
}

// ---------------------------------------------------------------------------
// Launch
// ---------------------------------------------------------------------------
extern "C" void kernel_launch(void* const* d_in, const int* in_sizes, int n_in,
                              void* d_out, int out_size, void* d_ws, size_t ws_size,
                              hipStream_t stream) {
    const int*   tokens = (const int*)  d_in[0];
    const float* emb    = (const float*)d_in[1];
    const float* w_ih   = (const float*)d_in[2];
    const float* w_hh   = (const float*)d_in[3];
    const float* b_ih   = (const float*)d_in[4];
    const float* b_hh   = (const float*)d_in[5];
    float* out = (float*)d_out;

    // ws layout: xproj fp16 (50.3 MB) | ring 128x128KB (16.8 MB) | flags+xpcnt
    _Float16* xproj16 = (_Float16*)d_ws;
    _Float16* ring    = xproj16 + (size_t)GRU_S * GRU_B * GRU_G;
    int*      flags   = (int*)(ring + 128 * (size_t)GRU_B * GRU_H);   // [64]
    int*      xpcnt   = flags + 64;                                   // [64]

    hipMemsetAsync(flags, 0, 128 * sizeof(int), stream);

    {
        const int* tok_a = tokens;
        const float* emb_a = emb;
        const float* wih_a = w_ih;
        const float* bih_a = b_ih;
        _Float16* xp_a = xproj16;
        const float* whh_a = w_hh;
        const float* bhh_a = b_hh;
        _Float16* ring_a = ring;
        float* out_a = out;
        int* flags_a = flags;
        int* xpcnt_a = xpcnt;
        void* args[] = { (void*)&tok_a, (void*)&emb_a, (void*)&wih_a,
                         (void*)&bih_a, (void*)&xp_a, (void*)&whh_a,
                         (void*)&bhh_a, (void*)&ring_a, (void*)&out_a,
                         (void*)&flags_a, (void*)&xpcnt_a };
        hipLaunchCooperativeKernel((void*)gru_fused, dim3(256), dim3(256),
                                   args, 0, stream);
    }
}